// Round 3
// baseline (154.677 us; speedup 1.0000x reference)
//
#include <hip/hip_runtime.h>
#include <math.h>

#define NATOMS 1024
#define NBATCH 16
#define T 64                               // tile edge
#define NTB (NATOMS / T)                   // 16 tile-blocks per dimension
#define TILES_PER_BATCH (NTB * (NTB + 1) / 2)   // 136 upper-triangle tiles

// Partial-sum slot layout in d_ws:
//   P[b][x][y][2][64]  -> phi[64] then rho[64]
// Slot (b,x,y) = contribution to atoms of row-block x of batch b coming from
// tile column-block y. Written exactly once per launch:
//   tile (ti,tj), ti<tj : row-sums -> slot (b,ti,tj), col-sums -> slot (b,tj,ti)
//   tile (ti,ti)        : full-tile row-sums -> slot (b,ti,ti)
// => all NTB*NTB slots per batch covered, no atomics, no zero-init needed.
#define PSLOT(b, x, y) ((((size_t)(b) * NTB + (x)) * NTB + (y)) * 128)

// Kernel 1: one block per upper-triangle 64x64 tile. Reads 53% of the
// symmetric distance matrix (34 MiB instead of 64 MiB).
__global__ __launch_bounds__(256) void eam_tile_kernel(
    const float* __restrict__ distances,
    const float* __restrict__ A,   const float* __restrict__ p,
    const float* __restrict__ xi,  const float* __restrict__ q,
    const float* __restrict__ r0,  const float* __restrict__ cut_a,
    const float* __restrict__ cut_b,
    const int* __restrict__ types,
    float* __restrict__ P)
{
    __shared__ int   lds_ti[T];
    __shared__ int   lds_tj[T];
    __shared__ float rsum[2][T];           // row sums (phi, rho)
    __shared__ float csum[2][16][T];       // col partials per ry-group

    const int tid = threadIdx.x;
    const int bid = blockIdx.x;
    const int b   = bid / TILES_PER_BATCH;
    int rem = bid - b * TILES_PER_BATCH;
    int ti  = 0;
    while (rem >= NTB - ti) { rem -= NTB - ti; ++ti; }   // uniform, <=16 iters
    const int tj = ti + rem;

    if (tid < T)            lds_ti[tid]     = types[b * NATOMS + ti * T + tid];
    else if (tid < 2 * T)   lds_tj[tid - T] = types[b * NATOMS + tj * T + (tid - T)];
    __syncthreads();

    // exp2-folded coefficients for the 3 pair types (pt = t_i + t_j, NT=2)
    const float L2E = 1.4426950408889634f;
    float Gp[3], Lp[3], Gr[3], Lr[3], iba[3], xo[3];
#pragma unroll
    for (int k = 0; k < 3; ++k) {
        Gp[k]  = -p[k] * L2E / r0[k];
        Lp[k]  = __log2f(A[k]) + p[k] * L2E;
        Gr[k]  = -2.0f * q[k] * L2E / r0[k];
        Lr[k]  = 2.0f * (__log2f(xi[k]) + q[k] * L2E);
        iba[k] = 1.0f / (cut_b[k] - cut_a[k]);
        xo[k]  = -cut_a[k] * iba[k];
    }

    const int cx = tid & 15;               // float4-column within tile
    const int ry = tid >> 4;               // row group (16 rows covered via s)

    const int4 tj4 = reinterpret_cast<const int4*>(lds_tj)[cx];
    const int  tjs[4] = {tj4.x, tj4.y, tj4.z, tj4.w};

    float cphi[4] = {0, 0, 0, 0};
    float crho[4] = {0, 0, 0, 0};

#pragma unroll
    for (int s = 0; s < 4; ++s) {
        const int   r_t = ry + 16 * s;     // row within tile
        const int   t_i = lds_ti[r_t];     // 16-lane broadcast

        // stage-1 select on t_i (once per 4 elements)
        const float GpL = t_i ? Gp[1] : Gp[0], GpH = t_i ? Gp[2] : Gp[1];
        const float LpL = t_i ? Lp[1] : Lp[0], LpH = t_i ? Lp[2] : Lp[1];
        const float GrL = t_i ? Gr[1] : Gr[0], GrH = t_i ? Gr[2] : Gr[1];
        const float LrL = t_i ? Lr[1] : Lr[0], LrH = t_i ? Lr[2] : Lr[1];
        const float ibL = t_i ? iba[1] : iba[0], ibH = t_i ? iba[2] : iba[1];
        const float xoL = t_i ? xo[1] : xo[0],  xoH = t_i ? xo[2] : xo[1];

        const float4 d4 = *reinterpret_cast<const float4*>(
            distances + ((size_t)(b * NATOMS + ti * T + r_t)) * NATOMS
                      + tj * T + cx * 4);
        const float rr[4] = {d4.x, d4.y, d4.z, d4.w};

        float rowp = 0.0f, rowr = 0.0f;
#pragma unroll
        for (int c = 0; c < 4; ++c) {
            const float r   = rr[c];
            const bool  hi  = (tjs[c] != 0);     // stage-2 select on t_j
            const float gp  = hi ? GpH : GpL;
            const float lp  = hi ? LpH : LpL;
            const float gr  = hi ? GrH : GrL;
            const float lr  = hi ? LrH : LrL;
            const float ib  = hi ? ibH : ibL;
            const float xof = hi ? xoH : xoL;

            const float x   = fmaf(r, ib, xof);
            const float xc  = fminf(fmaxf(x, 0.0f), 1.0f);   // diag r=100 -> fc=0
            const float fc  = fmaf(xc * xc, fmaf(2.0f, xc, -3.0f), 1.0f);
            const float e1  = __builtin_amdgcn_exp2f(fmaf(gp, r, lp));
            const float e2  = __builtin_amdgcn_exp2f(fmaf(gr, r, lr));
            const float phi = e1 * fc;
            const float rho = e2 * fc;
            rowp += phi;  rowr += rho;
            cphi[c] += phi;  crho[c] += rho;
        }

        // row-sum: reduce across the 16 cx lanes (xor stays inside group)
#pragma unroll
        for (int m = 8; m; m >>= 1) {
            rowp += __shfl_xor(rowp, m);
            rowr += __shfl_xor(rowr, m);
        }
        if (cx == 0) { rsum[0][r_t] = rowp; rsum[1][r_t] = rowr; }
    }

    // stash column partials (per ry group) for cross-group reduce
    *reinterpret_cast<float4*>(&csum[0][ry][cx * 4]) =
        make_float4(cphi[0], cphi[1], cphi[2], cphi[3]);
    *reinterpret_cast<float4*>(&csum[1][ry][cx * 4]) =
        make_float4(crho[0], crho[1], crho[2], crho[3]);
    __syncthreads();

    if (tid < 128) {
        // row-sum slot: contiguous 128-dword coalesced store
        const int which = tid >> 6, r = tid & 63;
        P[PSLOT(b, ti, tj) + which * 64 + r] = rsum[which][r];
    } else if (ti != tj) {
        // col-sum slot (symmetry): reduce 16 ry-groups, coalesced store
        const int h = tid - 128, which = h >> 6, col = h & 63;
        float s = 0.0f;
#pragma unroll
        for (int g = 0; g < 16; ++g) s += csum[which][g][col];
        P[PSLOT(b, tj, ti) + which * 64 + col] = s;
    }
}

// Kernel 2: one block per batch (1024 threads = 1 atom/thread).
// Sums the 16 partial contributions per atom, applies embedding, reduces.
__global__ __launch_bounds__(1024) void eam_finalize_kernel(
    const float* __restrict__ P,
    const float* __restrict__ emb_scale, const float* __restrict__ offset,
    const int* __restrict__ types,
    float* __restrict__ out)
{
    __shared__ float red[16];
    const int b = blockIdx.x;
    const int a = threadIdx.x;
    const int x = a >> 6, r = a & 63;

    float sphi = 0.0f, srho = 0.0f;
    const size_t base = PSLOT(b, x, 0) + r;
#pragma unroll
    for (int y = 0; y < NTB; ++y) {        // 64-dword coalesced per wave
        sphi += P[base + (size_t)y * 128];
        srho += P[base + (size_t)y * 128 + 64];
    }
    const int t = types[b * NATOMS + a];
    float e = 0.5f * sphi - emb_scale[t] * sqrtf(srho) + offset[t];

#pragma unroll
    for (int m = 32; m; m >>= 1) e += __shfl_down(e, m);
    if ((a & 63) == 0) red[a >> 6] = e;
    __syncthreads();
    if (a == 0) {
        float E = 0.0f;
#pragma unroll
        for (int i = 0; i < 16; ++i) E += red[i];
        out[b * 2]     = E;
        out[b * 2 + 1] = E * (1.0f / (float)NATOMS);   // n_atoms == N (t>=0)
    }
}

extern "C" void kernel_launch(void* const* d_in, const int* in_sizes, int n_in,
                              void* d_out, int out_size, void* d_ws, size_t ws_size,
                              hipStream_t stream) {
    const float* distances = (const float*)d_in[0];
    const float* A         = (const float*)d_in[1];
    const float* p         = (const float*)d_in[2];
    const float* xi        = (const float*)d_in[3];
    const float* q         = (const float*)d_in[4];
    const float* r0        = (const float*)d_in[5];
    const float* cut_a     = (const float*)d_in[6];
    const float* cut_b     = (const float*)d_in[7];
    const float* emb_scale = (const float*)d_in[8];
    const float* offset    = (const float*)d_in[9];
    const int*   types     = (const int*)d_in[10];
    // d_in[11] = pair_types : unused (recomputed from types; NT=2 -> pt=t_i+t_j)

    float* P   = (float*)d_ws;   // 2 MiB of partial slots; every slot rewritten
    float* out = (float*)d_out;

    eam_tile_kernel<<<NBATCH * TILES_PER_BATCH, 256, 0, stream>>>(
        distances, A, p, xi, q, r0, cut_a, cut_b, types, P);
    eam_finalize_kernel<<<NBATCH, 1024, 0, stream>>>(
        P, emb_scale, offset, types, out);
}